// Round 11
// baseline (276.976 us; speedup 1.0000x reference)
//
#include <hip/hip_runtime.h>
#include <hip/hip_fp16.h>

// ---------------------------------------------------------------------------
// GNN_6305011991202: 2-layer GraphSAGE (mean aggr) + linear head. fp32 I/O.
//   h1 = relu(mean1 @ W1_l^T + b1_l + x  @ W1_r^T)
//   h2 = relu(mean2 @ W2_l^T + b2_l + h1 @ W2_r^T)
//   out = h2 @ W3^T + b3          (out: [50000, 64] fp32)
// R11: 512-thread layer blocks (8 waves: wave gathers 2 nodes, computes 1
// col-tile) -> full 32-wave/CU occupancy + halved phase-1 latency chain.
// Head GEMM fused into layer 2 via LDS h2 tile (h2 never hits global).
// Gather path stays fp8(e4m3) rows (128B = 1 line); self/GEMM stay f16.
// ---------------------------------------------------------------------------

typedef _Float16 f16x8 __attribute__((ext_vector_type(8)));
typedef float floatx4 __attribute__((ext_vector_type(4)));
typedef float floatx2 __attribute__((ext_vector_type(2)));

__device__ __forceinline__ unsigned short f2h(float f) {
    __half h = __float2half_rn(f);
    union { __half h; unsigned short s; } c; c.h = h; return c.s;
}
__device__ __forceinline__ __half2 u2h(unsigned u) {
    union { unsigned u; __half2 h; } c; c.u = u; return c.h;
}
__device__ __forceinline__ unsigned h2u(__half2 h) {
    union { __half2 h; unsigned u; } c; c.h = h; return c.u;
}
__device__ __forceinline__ __half2 shx(__half2 v, int m) {
    return u2h((unsigned)__shfl_xor((int)h2u(v), m, 64));
}
__device__ __forceinline__ ushort4 cvt4h(float4 v) {
    ushort4 o;
    o.x = f2h(v.x); o.y = f2h(v.y); o.z = f2h(v.z); o.w = f2h(v.w);
    return o;
}
__device__ __forceinline__ unsigned char f2fp8(float v) {
    return (unsigned char)(__builtin_amdgcn_cvt_pk_fp8_f32(v, v, 0, false) & 0xff);
}

// ---------------------------------------------------------------------------
// Fused prologue: convert 5 weight mats (f16, contiguous dst), x -> f16 AND
// fp8 tables, zero deg.
#define WSEG 18432
__global__ __launch_bounds__(256) void prologue_kernel(
    const float* __restrict__ W1l, const float* __restrict__ W1r,
    const float* __restrict__ W2l, const float* __restrict__ W2r,
    const float* __restrict__ W3,  const float* __restrict__ x,
    unsigned short* __restrict__ wb,   // 5 weight dsts contiguous
    unsigned short* __restrict__ xb,
    unsigned char* __restrict__ x8,
    int* __restrict__ deg, int NX4, int ND4)
{
    int i = blockIdx.x * 256 + threadIdx.x;
    if (i < WSEG) {
        const float* s; int l;
        if (i < 8192)       { if (i < 4096) { s = W1l; l = i; }
                              else          { s = W1r; l = i - 4096; } }
        else if (i < 16384) { if (i < 12288){ s = W2l; l = i - 8192; }
                              else          { s = W2r; l = i - 12288; } }
        else                { s = W3; l = i - 16384; }
        ((ushort4*)wb)[i] = cvt4h(((const float4*)s)[l]);
        return;
    }
    int j = i - WSEG;
    if (j < NX4) {
        float4 v = ((const float4*)x)[j];
        ((ushort4*)xb)[j] = cvt4h(v);
        unsigned u8 = __builtin_amdgcn_cvt_pk_fp8_f32(v.x, v.y, 0, false);
        u8 = __builtin_amdgcn_cvt_pk_fp8_f32(v.z, v.w, u8, true);
        ((unsigned*)x8)[j] = u8;
        return;
    }
    int k = j - NX4;
    if (k < ND4) ((int4*)deg)[k] = make_int4(0, 0, 0, 0);
}

// ---------------------------------------------------------------------------
// CSR build step 1: degree histogram over dst
__global__ __launch_bounds__(256) void hist_kernel(const int* __restrict__ dst,
                                                   int* __restrict__ deg, int E) {
    int e = blockIdx.x * 256 + threadIdx.x;
    if (e < E) atomicAdd(deg + dst[e], 1);
}

// CSR scan A: per-block sums (1024 elems/block)
__global__ __launch_bounds__(256) void scan_partial_kernel(
    const int* __restrict__ deg, int* __restrict__ partials, int N)
{
    __shared__ int ws[4];
    const int t = threadIdx.x, lane = t & 63, wave = t >> 6;
    const int i4 = blockIdx.x * 256 + t;
    const int n4 = (N + 3) / 4;
    int s = 0;
    if (i4 < n4) {
        int b = i4 * 4;
        if (b + 3 < N) {
            int4 v = ((const int4*)deg)[i4];
            s = v.x + v.y + v.z + v.w;
        } else {
            for (int q = 0; q < 4 && b + q < N; ++q) s += deg[b + q];
        }
    }
#pragma unroll
    for (int off = 32; off > 0; off >>= 1) s += __shfl_xor(s, off, 64);
    if (lane == 0) ws[wave] = s;
    __syncthreads();
    if (t == 0) partials[blockIdx.x] = ws[0] + ws[1] + ws[2] + ws[3];
}

// CSR scan B+C merged: each block redundantly reduces partials[< blockIdx]
// (P <= 64), re-scans its 1024 elems, writes rowptr & cursor.
__global__ __launch_bounds__(256) void scan_apply_kernel(
    const int* __restrict__ deg, const int* __restrict__ partials,
    int* __restrict__ rowptr, int* __restrict__ cursor, int N, int P)
{
    __shared__ int woff[4];
    __shared__ int s_base;
    const int t = threadIdx.x, lane = t & 63, wave = t >> 6;
    const int i4 = blockIdx.x * 256 + t;
    const int n4 = (N + 3) / 4;
    const int b = i4 * 4;

    if (wave == 0) {          // exclusive sum of block partials below us
        int v = (lane < P && lane < (int)blockIdx.x) ? partials[lane] : 0;
#pragma unroll
        for (int off = 32; off > 0; off >>= 1) v += __shfl_xor(v, off, 64);
        if (lane == 0) s_base = v;
    }

    int4 v = make_int4(0, 0, 0, 0);
    if (i4 < n4) {
        if (b + 3 < N) v = ((const int4*)deg)[i4];
        else {
            if (b + 0 < N) v.x = deg[b + 0];
            if (b + 1 < N) v.y = deg[b + 1];
            if (b + 2 < N) v.z = deg[b + 2];
        }
    }
    const int p1 = v.x, p2 = v.x + v.y, p3 = v.x + v.y + v.z;
    const int tsum = p3 + v.w;
    int incl = tsum;
#pragma unroll
    for (int off = 1; off < 64; off <<= 1) {
        int tt = __shfl_up(incl, off, 64);
        if (lane >= off) incl += tt;
    }
    const int texcl = incl - tsum;
    if (lane == 63) woff[wave] = incl;
    __syncthreads();
    int wo = 0;
#pragma unroll
    for (int w = 0; w < 4; ++w) if (w < wave) wo += woff[w];
    const int e = s_base + wo + texcl;
    if (blockIdx.x == 0 && t == 0) rowptr[0] = 0;
    if (b + 3 < N) {
        ((int4*)cursor)[i4] = make_int4(e, e + p1, e + p2, e + p3);
        rowptr[b + 1] = e + p1;
        rowptr[b + 2] = e + p2;
        rowptr[b + 3] = e + p3;
        rowptr[b + 4] = e + tsum;
    } else if (b < N) {
        if (b + 0 < N) { cursor[b + 0] = e;      rowptr[b + 1] = e + p1; }
        if (b + 1 < N) { cursor[b + 1] = e + p1; rowptr[b + 2] = e + p2; }
        if (b + 2 < N) { cursor[b + 2] = e + p2; rowptr[b + 3] = e + p3; }
    }
}

// CSR build: scatter src ids into neighbor lists
__global__ __launch_bounds__(256) void fill_kernel(const int* __restrict__ src,
                                                   const int* __restrict__ dst,
                                                   int* __restrict__ cursor,
                                                   int* __restrict__ csr, int E) {
    int e = blockIdx.x * 256 + threadIdx.x;
    if (e >= E) return;
    int pos = atomicAdd(cursor + dst[e], 1);
    csr[pos] = src[e];
}

// ---------------------------------------------------------------------------
// Fused SAGE layer (+optional head): 512 threads = 8 waves per 16-row tile.
// Phase 1: wave w gathers nodes r0+2w, r0+2w+1. Lane = (nbr slot grp =
//   lane>>4, col group = lane&15 covering 8 fp8 cols / 8B). One dwordx2
//   wave-load fetches 4 neighbor fp8 rows (128B = 1 line each); HW
//   cvt_pk_f32_fp8 unpack + v_pk_add_f32. OOB slots clamp + zero-mask.
//   Node end: pack f16, shfl_xor(16/32) cross-slot reduce, grp==0 -> LDS.
// Phase 2: wave w computes col-tile w (16 cols) with mfma_f32_16x16x32_f16:
//   A (mean) from LDS, self f16 from global, dual Wl/Wr accumulate.
//   !HEAD: store f16 out (+fp8 copy if WFP8). HEAD: store h2 tile to LDS,
//   barrier, waves 0-3 run the 64-col head GEMM (A=sh2, B=W3) -> fp32 out.
template <bool WFP8, bool HEAD>
__global__ __launch_bounds__(512) void sage_layer_kernel(
    const unsigned short* __restrict__ feat,   // [N,128] f16 (self path)
    const unsigned char* __restrict__ feat8,   // [N,128] fp8 (gather path)
    const int* __restrict__ rowptr, const int* __restrict__ csr,
    const unsigned short* __restrict__ Wl,
    const unsigned short* __restrict__ Wr,
    const float* __restrict__ bias,
    unsigned short* __restrict__ out,          // [N,128] f16 (if !HEAD)
    unsigned char* __restrict__ out8,          // [N,128] fp8 (if WFP8)
    const unsigned short* __restrict__ W3,     // [64,128] f16 (if HEAD)
    const float* __restrict__ b3,              // [64] (if HEAD)
    float* __restrict__ outF,                  // [N,64] fp32 (if HEAD)
    int N)
{
    __shared__ unsigned short smean[16][136];
    __shared__ unsigned short sh2[16][136];    // used only if HEAD
    const int wave = threadIdx.x >> 6;         // 0..7
    const int lane = threadIdx.x & 63;
    const int r0 = blockIdx.x * 16;

    // ---- phase 1: this wave gathers 2 of the block's 16 nodes ----
    {
        const int grp = lane >> 4;          // neighbor slot
        const int col = lane & 15;          // 8-col group (8B of fp8)
        const unsigned char* fq = feat8 + col * 8;
#pragma unroll
        for (int q = 0; q < 2; ++q) {
            const int mi = wave * 2 + q;
            const int n = r0 + mi;
            if (n >= N) break;
            const int beg = rowptr[n], end = rowptr[n + 1];
            const int deg = end - beg;
            floatx2 a0 = (floatx2)(0.f), a1 = (floatx2)(0.f);
            floatx2 a2 = (floatx2)(0.f), a3 = (floatx2)(0.f);
            // chunks of 4 neighbors per slot; 16 neighbors in flight
            for (int jA = beg + grp; jA < end; jA += 16) {
                const int jB = jA + 4, jC = jA + 8, jD = jA + 12;
                const unsigned mB = (jB < end) ? 0xffffffffu : 0u;
                const unsigned mC = (jC < end) ? 0xffffffffu : 0u;
                const unsigned mD = (jD < end) ? 0xffffffffu : 0u;
                const int iA = csr[jA];
                const int iB = csr[mB ? jB : beg];
                const int iC = csr[mC ? jC : beg];
                const int iD = csr[mD ? jD : beg];
                uint2 pA = *(const uint2*)(fq + (size_t)iA * 128);
                uint2 pB = *(const uint2*)(fq + (size_t)iB * 128);
                uint2 pC = *(const uint2*)(fq + (size_t)iC * 128);
                uint2 pD = *(const uint2*)(fq + (size_t)iD * 128);
                pB.x &= mB; pB.y &= mB;
                pC.x &= mC; pC.y &= mC;
                pD.x &= mD; pD.y &= mD;
                a0 += __builtin_amdgcn_cvt_pk_f32_fp8(pA.x, false);
                a1 += __builtin_amdgcn_cvt_pk_f32_fp8(pA.x, true);
                a2 += __builtin_amdgcn_cvt_pk_f32_fp8(pA.y, false);
                a3 += __builtin_amdgcn_cvt_pk_f32_fp8(pA.y, true);
                a0 += __builtin_amdgcn_cvt_pk_f32_fp8(pB.x, false);
                a1 += __builtin_amdgcn_cvt_pk_f32_fp8(pB.x, true);
                a2 += __builtin_amdgcn_cvt_pk_f32_fp8(pB.y, false);
                a3 += __builtin_amdgcn_cvt_pk_f32_fp8(pB.y, true);
                a0 += __builtin_amdgcn_cvt_pk_f32_fp8(pC.x, false);
                a1 += __builtin_amdgcn_cvt_pk_f32_fp8(pC.x, true);
                a2 += __builtin_amdgcn_cvt_pk_f32_fp8(pC.y, false);
                a3 += __builtin_amdgcn_cvt_pk_f32_fp8(pC.y, true);
                a0 += __builtin_amdgcn_cvt_pk_f32_fp8(pD.x, false);
                a1 += __builtin_amdgcn_cvt_pk_f32_fp8(pD.x, true);
                a2 += __builtin_amdgcn_cvt_pk_f32_fp8(pD.y, false);
                a3 += __builtin_amdgcn_cvt_pk_f32_fp8(pD.y, true);
            }
            // pack partial f32 sums -> f16 pairs, packed cross-slot reduce
            __half2 c0 = __floats2half2_rn(a0.x, a0.y);
            __half2 c1 = __floats2half2_rn(a1.x, a1.y);
            __half2 c2 = __floats2half2_rn(a2.x, a2.y);
            __half2 c3 = __floats2half2_rn(a3.x, a3.y);
            c0 = __hadd2(c0, shx(c0, 16)); c0 = __hadd2(c0, shx(c0, 32));
            c1 = __hadd2(c1, shx(c1, 16)); c1 = __hadd2(c1, shx(c1, 32));
            c2 = __hadd2(c2, shx(c2, 16)); c2 = __hadd2(c2, shx(c2, 32));
            c3 = __hadd2(c3, shx(c3, 16)); c3 = __hadd2(c3, shx(c3, 32));
            if (grp == 0) {
                const float inv = (deg > 0) ? 1.0f / (float)deg : 0.0f;
                uint4 o;
                o.x = h2u(__floats2half2_rn(__low2float(c0) * inv,
                                            __high2float(c0) * inv));
                o.y = h2u(__floats2half2_rn(__low2float(c1) * inv,
                                            __high2float(c1) * inv));
                o.z = h2u(__floats2half2_rn(__low2float(c2) * inv,
                                            __high2float(c2) * inv));
                o.w = h2u(__floats2half2_rn(__low2float(c3) * inv,
                                            __high2float(c3) * inv));
                *(uint4*)&smean[mi][col * 8] = o;
            }
        }
    }
    __syncthreads();

    // ---- phase 2: this wave computes col-tile `wave` ----
    const int mrow = lane & 15;
    const int quad = lane >> 4;
    int selfRow = r0 + mrow;
    if (selfRow >= N) selfRow = N - 1;      // partial-tile clamp (loads only)
    const size_t rowS = (size_t)selfRow * 128;

    floatx4 acc = (floatx4)(0.0f);
    const int t0 = wave;

#pragma unroll
    for (int kk = 0; kk < 4; ++kk) {
        const int k = kk * 32 + quad * 8;
        f16x8 aA = *(const f16x8*)&smean[mrow][k];
        f16x8 aS = *(const f16x8*)(feat + rowS + k);
        f16x8 bl = *(const f16x8*)(Wl + (size_t)(t0 * 16 + mrow) * 128 + k);
        acc = __builtin_amdgcn_mfma_f32_16x16x32_f16(aA, bl, acc, 0, 0, 0);
        f16x8 br = *(const f16x8*)(Wr + (size_t)(t0 * 16 + mrow) * 128 + k);
        acc = __builtin_amdgcn_mfma_f32_16x16x32_f16(aS, br, acc, 0, 0, 0);
    }

    const float b0 = bias[t0 * 16 + mrow];
#pragma unroll
    for (int i = 0; i < 4; ++i) {
        const int r = r0 + quad * 4 + i;
        const float v = fmaxf(acc[i] + b0, 0.0f);
        if (HEAD) {
            sh2[quad * 4 + i][t0 * 16 + mrow] = f2h(v);
        } else if (r < N) {
            out[(size_t)r * 128 + t0 * 16 + mrow] = f2h(v);
            if (WFP8) out8[(size_t)r * 128 + t0 * 16 + mrow] = f2fp8(v);
        }
    }

    // ---- optional fused head: out = h2 @ W3^T + b3 (fp32, 64 cols) ----
    if (HEAD) {
        __syncthreads();
        if (wave < 4) {
            floatx4 ah = (floatx4)(0.0f);
#pragma unroll
            for (int kk = 0; kk < 4; ++kk) {
                const int k = kk * 32 + quad * 8;
                f16x8 aA = *(const f16x8*)&sh2[mrow][k];
                f16x8 b = *(const f16x8*)(W3 + (size_t)(wave * 16 + mrow) * 128 + k);
                ah = __builtin_amdgcn_mfma_f32_16x16x32_f16(aA, b, ah, 0, 0, 0);
            }
            const float bh = b3[wave * 16 + mrow];
#pragma unroll
            for (int i = 0; i < 4; ++i) {
                const int r = r0 + quad * 4 + i;
                if (r < N)
                    outF[(size_t)r * 64 + wave * 16 + mrow] = ah[i] + bh;
            }
        }
    }
}

// ---------------------------------------------------------------------------
extern "C" void kernel_launch(void* const* d_in, const int* in_sizes, int n_in,
                              void* d_out, int out_size, void* d_ws, size_t ws_size,
                              hipStream_t stream)
{
    const float* x   = (const float*)d_in[0];
    const int* ei    = (const int*)d_in[1];
    const float* W1l = (const float*)d_in[2];
    const float* b1l = (const float*)d_in[3];
    const float* W1r = (const float*)d_in[4];
    const float* W2l = (const float*)d_in[5];
    const float* b2l = (const float*)d_in[6];
    const float* W2r = (const float*)d_in[7];
    const float* W3  = (const float*)d_in[8];
    const float* b3  = (const float*)d_in[9];
    float* out = (float*)d_out;

    const int N = in_sizes[0] / 128;   // 50000
    const int E = in_sizes[1] / 2;     // 640000
    const int* src = ei;
    const int* dst = ei + E;

    // workspace layout (all offsets 16B aligned):
    //   deg_i : n4*4 ints        partials: 64 ints
    //   rowptr: N+4 ints         cursor  : n4*4 ints
    //   csr   : E ints           xb/h1   : N*128 f16 each
    //   wb    : 5 f16 weight mats contiguous
    //   x8/h18: N*128 fp8 each (gather tables)
    const int n4 = (N + 3) / 4;
    int* deg_i    = (int*)d_ws;
    int* partials = deg_i + n4 * 4;
    int* rowptr   = partials + 64;
    int* cursor   = rowptr + N + 4;
    int* csr      = cursor + n4 * 4;
    unsigned short* xb   = (unsigned short*)(csr + E);
    unsigned short* h1   = xb + (size_t)N * 128;
    unsigned short* wb1l = h1 + (size_t)N * 128;
    unsigned short* wb1r = wb1l + 16384;
    unsigned short* wb2l = wb1r + 16384;
    unsigned short* wb2r = wb2l + 16384;
    unsigned short* wb3  = wb2r + 16384;
    unsigned char* x8    = (unsigned char*)(wb3 + 8192);
    unsigned char* h18   = x8 + (size_t)N * 128;

    const int lblk = (N + 15) / 16;             // fused layer: 1 tile/block
    const int eblk = (E + 255) / 256;
    const int NX4  = N * 32;                    // x in float4 units
    const int P    = (n4 + 255) / 256;          // scan blocks (<=64 for N<=65536)

    // ---- fused prologue: weight cvt + x cvt (f16+fp8) + deg zero ----
    {
        int total = WSEG + NX4 + n4;
        hipLaunchKernelGGL(prologue_kernel, dim3((total + 255) / 256), dim3(256), 0,
                           stream, W1l, W1r, W2l, W2r, W3, x, wb1l, xb, x8, deg_i,
                           NX4, n4);
    }

    // ---- CSR build (once; reused by both layers) ----
    hipLaunchKernelGGL(hist_kernel, dim3(eblk), dim3(256), 0, stream, dst, deg_i, E);
    hipLaunchKernelGGL(scan_partial_kernel, dim3(P), dim3(256), 0, stream,
                       deg_i, partials, N);
    hipLaunchKernelGGL(scan_apply_kernel, dim3(P), dim3(256), 0, stream,
                       deg_i, partials, rowptr, cursor, N, P);
    hipLaunchKernelGGL(fill_kernel, dim3(eblk), dim3(256), 0, stream,
                       src, dst, cursor, csr, E);

    // ---- fused layers (layer 2 carries the head) ----
    hipLaunchKernelGGL((sage_layer_kernel<true, false>), dim3(lblk), dim3(512), 0,
                       stream, xb, x8, rowptr, csr, wb1l, wb1r, b1l,
                       h1, h18, nullptr, nullptr, nullptr, N);
    hipLaunchKernelGGL((sage_layer_kernel<false, true>), dim3(lblk), dim3(512), 0,
                       stream, h1, h18, rowptr, csr, wb2l, wb2r, b2l,
                       nullptr, nullptr, wb3, b3, out, N);
}

// Round 12
// 262.981 us; speedup vs baseline: 1.0532x; 1.0532x over previous
//
#include <hip/hip_runtime.h>
#include <hip/hip_fp16.h>

// ---------------------------------------------------------------------------
// GNN_6305011991202: 2-layer GraphSAGE (mean aggr) + linear head. fp32 I/O.
//   h1 = relu(mean1 @ W1_l^T + b1_l + x  @ W1_r^T)
//   h2 = relu(mean2 @ W2_l^T + b2_l + h1 @ W2_r^T)
//   out = h2 @ W3^T + b3          (out: [50000, 64] fp32)
// R12: R10 structure (256 thr, 4 waves x 4 nodes, 2 col-tiles/wave) +
//   (1) batched phase-1 chains: rowptr window scalar-loaded once, all 16 csr
//       index loads then all 16 feat loads issued back-to-back (~51 rows in
//       flight per wave vs ~13), consumed in issue order;
//   (2) head GEMM fused into layer 2 via LDS h2 tile (no h2 global, no 8th
//       launch). Gather table fp8 e4m3 (128B rows); self/GEMMs f16.
// ---------------------------------------------------------------------------

typedef _Float16 f16x8 __attribute__((ext_vector_type(8)));
typedef float floatx4 __attribute__((ext_vector_type(4)));
typedef float floatx2 __attribute__((ext_vector_type(2)));

__device__ __forceinline__ unsigned short f2h(float f) {
    __half h = __float2half_rn(f);
    union { __half h; unsigned short s; } c; c.h = h; return c.s;
}
__device__ __forceinline__ __half2 u2h(unsigned u) {
    union { unsigned u; __half2 h; } c; c.u = u; return c.h;
}
__device__ __forceinline__ unsigned h2u(__half2 h) {
    union { __half2 h; unsigned u; } c; c.h = h; return c.u;
}
__device__ __forceinline__ __half2 shx(__half2 v, int m) {
    return u2h((unsigned)__shfl_xor((int)h2u(v), m, 64));
}
__device__ __forceinline__ ushort4 cvt4h(float4 v) {
    ushort4 o;
    o.x = f2h(v.x); o.y = f2h(v.y); o.z = f2h(v.z); o.w = f2h(v.w);
    return o;
}
__device__ __forceinline__ unsigned char f2fp8(float v) {
    return (unsigned char)(__builtin_amdgcn_cvt_pk_fp8_f32(v, v, 0, false) & 0xff);
}

// ---------------------------------------------------------------------------
// Fused prologue: convert 5 weight mats (f16, contiguous dst), x -> f16 AND
// fp8 tables, zero deg.
#define WSEG 18432
__global__ __launch_bounds__(256) void prologue_kernel(
    const float* __restrict__ W1l, const float* __restrict__ W1r,
    const float* __restrict__ W2l, const float* __restrict__ W2r,
    const float* __restrict__ W3,  const float* __restrict__ x,
    unsigned short* __restrict__ wb,   // 5 weight dsts contiguous
    unsigned short* __restrict__ xb,
    unsigned char* __restrict__ x8,
    int* __restrict__ deg, int NX4, int ND4)
{
    int i = blockIdx.x * 256 + threadIdx.x;
    if (i < WSEG) {
        const float* s; int l;
        if (i < 8192)       { if (i < 4096) { s = W1l; l = i; }
                              else          { s = W1r; l = i - 4096; } }
        else if (i < 16384) { if (i < 12288){ s = W2l; l = i - 8192; }
                              else          { s = W2r; l = i - 12288; } }
        else                { s = W3; l = i - 16384; }
        ((ushort4*)wb)[i] = cvt4h(((const float4*)s)[l]);
        return;
    }
    int j = i - WSEG;
    if (j < NX4) {
        float4 v = ((const float4*)x)[j];
        ((ushort4*)xb)[j] = cvt4h(v);
        unsigned u8 = __builtin_amdgcn_cvt_pk_fp8_f32(v.x, v.y, 0, false);
        u8 = __builtin_amdgcn_cvt_pk_fp8_f32(v.z, v.w, u8, true);
        ((unsigned*)x8)[j] = u8;
        return;
    }
    int k = j - NX4;
    if (k < ND4) ((int4*)deg)[k] = make_int4(0, 0, 0, 0);
}

// ---------------------------------------------------------------------------
// CSR build step 1: degree histogram over dst
__global__ __launch_bounds__(256) void hist_kernel(const int* __restrict__ dst,
                                                   int* __restrict__ deg, int E) {
    int e = blockIdx.x * 256 + threadIdx.x;
    if (e < E) atomicAdd(deg + dst[e], 1);
}

// CSR scan A: per-block sums (1024 elems/block)
__global__ __launch_bounds__(256) void scan_partial_kernel(
    const int* __restrict__ deg, int* __restrict__ partials, int N)
{
    __shared__ int ws[4];
    const int t = threadIdx.x, lane = t & 63, wave = t >> 6;
    const int i4 = blockIdx.x * 256 + t;
    const int n4 = (N + 3) / 4;
    int s = 0;
    if (i4 < n4) {
        int b = i4 * 4;
        if (b + 3 < N) {
            int4 v = ((const int4*)deg)[i4];
            s = v.x + v.y + v.z + v.w;
        } else {
            for (int q = 0; q < 4 && b + q < N; ++q) s += deg[b + q];
        }
    }
#pragma unroll
    for (int off = 32; off > 0; off >>= 1) s += __shfl_xor(s, off, 64);
    if (lane == 0) ws[wave] = s;
    __syncthreads();
    if (t == 0) partials[blockIdx.x] = ws[0] + ws[1] + ws[2] + ws[3];
}

// CSR scan B+C merged: each block redundantly reduces partials[< blockIdx]
// (P <= 64), re-scans its 1024 elems, writes rowptr & cursor.
__global__ __launch_bounds__(256) void scan_apply_kernel(
    const int* __restrict__ deg, const int* __restrict__ partials,
    int* __restrict__ rowptr, int* __restrict__ cursor, int N, int P)
{
    __shared__ int woff[4];
    __shared__ int s_base;
    const int t = threadIdx.x, lane = t & 63, wave = t >> 6;
    const int i4 = blockIdx.x * 256 + t;
    const int n4 = (N + 3) / 4;
    const int b = i4 * 4;

    if (wave == 0) {          // exclusive sum of block partials below us
        int v = (lane < P && lane < (int)blockIdx.x) ? partials[lane] : 0;
#pragma unroll
        for (int off = 32; off > 0; off >>= 1) v += __shfl_xor(v, off, 64);
        if (lane == 0) s_base = v;
    }

    int4 v = make_int4(0, 0, 0, 0);
    if (i4 < n4) {
        if (b + 3 < N) v = ((const int4*)deg)[i4];
        else {
            if (b + 0 < N) v.x = deg[b + 0];
            if (b + 1 < N) v.y = deg[b + 1];
            if (b + 2 < N) v.z = deg[b + 2];
        }
    }
    const int p1 = v.x, p2 = v.x + v.y, p3 = v.x + v.y + v.z;
    const int tsum = p3 + v.w;
    int incl = tsum;
#pragma unroll
    for (int off = 1; off < 64; off <<= 1) {
        int tt = __shfl_up(incl, off, 64);
        if (lane >= off) incl += tt;
    }
    const int texcl = incl - tsum;
    if (lane == 63) woff[wave] = incl;
    __syncthreads();
    int wo = 0;
#pragma unroll
    for (int w = 0; w < 4; ++w) if (w < wave) wo += woff[w];
    const int e = s_base + wo + texcl;
    if (blockIdx.x == 0 && t == 0) rowptr[0] = 0;
    if (b + 3 < N) {
        ((int4*)cursor)[i4] = make_int4(e, e + p1, e + p2, e + p3);
        rowptr[b + 1] = e + p1;
        rowptr[b + 2] = e + p2;
        rowptr[b + 3] = e + p3;
        rowptr[b + 4] = e + tsum;
    } else if (b < N) {
        if (b + 0 < N) { cursor[b + 0] = e;      rowptr[b + 1] = e + p1; }
        if (b + 1 < N) { cursor[b + 1] = e + p1; rowptr[b + 2] = e + p2; }
        if (b + 2 < N) { cursor[b + 2] = e + p2; rowptr[b + 3] = e + p3; }
    }
}

// CSR build: scatter src ids into neighbor lists
__global__ __launch_bounds__(256) void fill_kernel(const int* __restrict__ src,
                                                   const int* __restrict__ dst,
                                                   int* __restrict__ cursor,
                                                   int* __restrict__ csr, int E) {
    int e = blockIdx.x * 256 + threadIdx.x;
    if (e >= E) return;
    int pos = atomicAdd(cursor + dst[e], 1);
    csr[pos] = src[e];
}

// ---------------------------------------------------------------------------
// Fused SAGE layer (+optional head): 256 threads = 4 waves per 16-row tile.
// Phase 1 (wave w -> nodes r0+4w..+3), BATCHED dependent chains:
//   1. scalar-load the 5-entry rowptr window (one round-trip).
//   2. issue ALL 16 csr-index loads (4 nodes x 4 chunk-slots) back-to-back.
//   3. issue ALL 16 feat dwordx2 loads back-to-back (~51 rows in flight).
//   4. consume node-by-node in issue order (compiler emits fine vmcnt),
//      OOB chunk zero-masked; tail loop (deg>16, ~18% of nodes) uses R10's
//      exact chunk order -> summation order identical to R10.
//   Node end: pack f16, shfl_xor(16/32) cross-slot reduce, grp==0 -> LDS.
// Phase 2: wave w computes col-tiles {2w,2w+1} (dual Wl/Wr MFMA,
//   mfma_f32_16x16x32_f16), A from LDS, self f16 from global.
//   !HEAD: store f16 out (+fp8 copy if WFP8). HEAD: h2 tile -> LDS, barrier,
//   each wave does one 16-col head tile (A=sh2, B=W3) -> fp32 out.
template <bool WFP8, bool HEAD>
__global__ __launch_bounds__(256) void sage_layer_kernel(
    const unsigned short* __restrict__ feat,   // [N,128] f16 (self path)
    const unsigned char* __restrict__ feat8,   // [N,128] fp8 (gather path)
    const int* __restrict__ rowptr, const int* __restrict__ csr,
    const unsigned short* __restrict__ Wl,
    const unsigned short* __restrict__ Wr,
    const float* __restrict__ bias,
    unsigned short* __restrict__ out,          // [N,128] f16 (if !HEAD)
    unsigned char* __restrict__ out8,          // [N,128] fp8 (if WFP8)
    const unsigned short* __restrict__ W3,     // [64,128] f16 (if HEAD)
    const float* __restrict__ b3,              // [64] (if HEAD)
    float* __restrict__ outF,                  // [N,64] fp32 (if HEAD)
    int N)
{
    __shared__ unsigned short smean[16][136];
    __shared__ unsigned short sh2[HEAD ? 16 : 1][136];
    const int wave = threadIdx.x >> 6;
    const int lane = threadIdx.x & 63;
    const int r0 = blockIdx.x * 16;

    // ---- phase 1: this wave gathers 4 of the block's 16 nodes ----
    {
        const int grp = lane >> 4;          // neighbor slot 0..3
        const int col = lane & 15;          // 8-col group (8B of fp8)
        const unsigned char* fq = feat8 + col * 8;

        // 1. rowptr window (wave-uniform -> scalar loads, all in flight)
        int w[5];
#pragma unroll
        for (int q = 0; q < 5; ++q) {
            int n = r0 + wave * 4 + q;
            w[q] = rowptr[n < N ? n : N];   // rowptr has N+1 valid entries
        }

        // 2. all csr index loads (16) back-to-back
        int idx[4][4];
#pragma unroll
        for (int q = 0; q < 4; ++q)
#pragma unroll
            for (int c = 0; c < 4; ++c) {
                const int j = w[q] + grp + c * 4;
                idx[q][c] = csr[j < w[q + 1] ? j : 0];
            }

        // 3. all feat loads (16) back-to-back (~51 rows in flight)
        uint2 pay[4][4];
#pragma unroll
        for (int q = 0; q < 4; ++q)
#pragma unroll
            for (int c = 0; c < 4; ++c)
                pay[q][c] = *(const uint2*)(fq + (size_t)idx[q][c] * 128);

        // 4. consume node-by-node in issue order
#pragma unroll
        for (int q = 0; q < 4; ++q) {
            const int mi = wave * 4 + q;
            const int beg = w[q], end = w[q + 1];
            const int deg = end - beg;
            floatx2 a0 = (floatx2)(0.f), a1 = (floatx2)(0.f);
            floatx2 a2 = (floatx2)(0.f), a3 = (floatx2)(0.f);
#pragma unroll
            for (int c = 0; c < 4; ++c) {
                const int j = beg + grp + c * 4;
                const unsigned m = (j < end) ? 0xffffffffu : 0u;
                uint2 p = pay[q][c];
                p.x &= m; p.y &= m;
                a0 += __builtin_amdgcn_cvt_pk_f32_fp8(p.x, false);
                a1 += __builtin_amdgcn_cvt_pk_f32_fp8(p.x, true);
                a2 += __builtin_amdgcn_cvt_pk_f32_fp8(p.y, false);
                a3 += __builtin_amdgcn_cvt_pk_f32_fp8(p.y, true);
            }
            // tail: deg > 16 (same chunk order as R10's later iterations)
            for (int jA = beg + 16 + grp; jA < end; jA += 16) {
                const int jB = jA + 4, jC = jA + 8, jD = jA + 12;
                const unsigned mB = (jB < end) ? 0xffffffffu : 0u;
                const unsigned mC = (jC < end) ? 0xffffffffu : 0u;
                const unsigned mD = (jD < end) ? 0xffffffffu : 0u;
                const int iA = csr[jA];
                const int iB = csr[mB ? jB : beg];
                const int iC = csr[mC ? jC : beg];
                const int iD = csr[mD ? jD : beg];
                uint2 pA = *(const uint2*)(fq + (size_t)iA * 128);
                uint2 pB = *(const uint2*)(fq + (size_t)iB * 128);
                uint2 pC = *(const uint2*)(fq + (size_t)iC * 128);
                uint2 pD = *(const uint2*)(fq + (size_t)iD * 128);
                pB.x &= mB; pB.y &= mB;
                pC.x &= mC; pC.y &= mC;
                pD.x &= mD; pD.y &= mD;
                a0 += __builtin_amdgcn_cvt_pk_f32_fp8(pA.x, false);
                a1 += __builtin_amdgcn_cvt_pk_f32_fp8(pA.x, true);
                a2 += __builtin_amdgcn_cvt_pk_f32_fp8(pA.y, false);
                a3 += __builtin_amdgcn_cvt_pk_f32_fp8(pA.y, true);
                a0 += __builtin_amdgcn_cvt_pk_f32_fp8(pB.x, false);
                a1 += __builtin_amdgcn_cvt_pk_f32_fp8(pB.x, true);
                a2 += __builtin_amdgcn_cvt_pk_f32_fp8(pB.y, false);
                a3 += __builtin_amdgcn_cvt_pk_f32_fp8(pB.y, true);
                a0 += __builtin_amdgcn_cvt_pk_f32_fp8(pC.x, false);
                a1 += __builtin_amdgcn_cvt_pk_f32_fp8(pC.x, true);
                a2 += __builtin_amdgcn_cvt_pk_f32_fp8(pC.y, false);
                a3 += __builtin_amdgcn_cvt_pk_f32_fp8(pC.y, true);
                a0 += __builtin_amdgcn_cvt_pk_f32_fp8(pD.x, false);
                a1 += __builtin_amdgcn_cvt_pk_f32_fp8(pD.x, true);
                a2 += __builtin_amdgcn_cvt_pk_f32_fp8(pD.y, false);
                a3 += __builtin_amdgcn_cvt_pk_f32_fp8(pD.y, true);
            }
            // pack partial f32 sums -> f16 pairs, packed cross-slot reduce
            __half2 c0 = __floats2half2_rn(a0.x, a0.y);
            __half2 c1 = __floats2half2_rn(a1.x, a1.y);
            __half2 c2 = __floats2half2_rn(a2.x, a2.y);
            __half2 c3 = __floats2half2_rn(a3.x, a3.y);
            c0 = __hadd2(c0, shx(c0, 16)); c0 = __hadd2(c0, shx(c0, 32));
            c1 = __hadd2(c1, shx(c1, 16)); c1 = __hadd2(c1, shx(c1, 32));
            c2 = __hadd2(c2, shx(c2, 16)); c2 = __hadd2(c2, shx(c2, 32));
            c3 = __hadd2(c3, shx(c3, 16)); c3 = __hadd2(c3, shx(c3, 32));
            if (grp == 0) {
                const float inv = (deg > 0) ? 1.0f / (float)deg : 0.0f;
                uint4 o;
                o.x = h2u(__floats2half2_rn(__low2float(c0) * inv,
                                            __high2float(c0) * inv));
                o.y = h2u(__floats2half2_rn(__low2float(c1) * inv,
                                            __high2float(c1) * inv));
                o.z = h2u(__floats2half2_rn(__low2float(c2) * inv,
                                            __high2float(c2) * inv));
                o.w = h2u(__floats2half2_rn(__low2float(c3) * inv,
                                            __high2float(c3) * inv));
                *(uint4*)&smean[mi][col * 8] = o;
            }
        }
    }
    __syncthreads();

    // ---- phase 2: this wave computes col-tiles 2*wave, 2*wave+1 ----
    const int mrow = lane & 15;
    const int quad = lane >> 4;
    int selfRow = r0 + mrow;
    if (selfRow >= N) selfRow = N - 1;      // partial-tile clamp (loads only)
    const size_t rowS = (size_t)selfRow * 128;

    floatx4 acc0 = (floatx4)(0.0f), acc1 = (floatx4)(0.0f);
    const int t0 = wave * 2, t1 = wave * 2 + 1;

#pragma unroll
    for (int kk = 0; kk < 4; ++kk) {
        const int k = kk * 32 + quad * 8;
        f16x8 aA = *(const f16x8*)&smean[mrow][k];
        f16x8 aS = *(const f16x8*)(feat + rowS + k);
        f16x8 bl0 = *(const f16x8*)(Wl + (size_t)(t0 * 16 + mrow) * 128 + k);
        acc0 = __builtin_amdgcn_mfma_f32_16x16x32_f16(aA, bl0, acc0, 0, 0, 0);
        f16x8 br0 = *(const f16x8*)(Wr + (size_t)(t0 * 16 + mrow) * 128 + k);
        acc0 = __builtin_amdgcn_mfma_f32_16x16x32_f16(aS, br0, acc0, 0, 0, 0);
        f16x8 bl1 = *(const f16x8*)(Wl + (size_t)(t1 * 16 + mrow) * 128 + k);
        acc1 = __builtin_amdgcn_mfma_f32_16x16x32_f16(aA, bl1, acc1, 0, 0, 0);
        f16x8 br1 = *(const f16x8*)(Wr + (size_t)(t1 * 16 + mrow) * 128 + k);
        acc1 = __builtin_amdgcn_mfma_f32_16x16x32_f16(aS, br1, acc1, 0, 0, 0);
    }

    const float b0 = bias[t0 * 16 + mrow];
    const float b1 = bias[t1 * 16 + mrow];
#pragma unroll
    for (int i = 0; i < 4; ++i) {
        const int r = r0 + quad * 4 + i;
        const float v0 = fmaxf(acc0[i] + b0, 0.0f);
        const float v1 = fmaxf(acc1[i] + b1, 0.0f);
        if (HEAD) {
            sh2[quad * 4 + i][t0 * 16 + mrow] = f2h(v0);
            sh2[quad * 4 + i][t1 * 16 + mrow] = f2h(v1);
        } else if (r < N) {
            out[(size_t)r * 128 + t0 * 16 + mrow] = f2h(v0);
            out[(size_t)r * 128 + t1 * 16 + mrow] = f2h(v1);
            if (WFP8) {
                out8[(size_t)r * 128 + t0 * 16 + mrow] = f2fp8(v0);
                out8[(size_t)r * 128 + t1 * 16 + mrow] = f2fp8(v1);
            }
        }
    }

    // ---- optional fused head: out = h2 @ W3^T + b3 (fp32, 64 cols) ----
    if (HEAD) {
        __syncthreads();
        floatx4 ah = (floatx4)(0.0f);
#pragma unroll
        for (int kk = 0; kk < 4; ++kk) {
            const int k = kk * 32 + quad * 8;
            f16x8 aA = *(const f16x8*)&sh2[mrow][k];
            f16x8 b = *(const f16x8*)(W3 + (size_t)(wave * 16 + mrow) * 128 + k);
            ah = __builtin_amdgcn_mfma_f32_16x16x32_f16(aA, b, ah, 0, 0, 0);
        }
        const float bh = b3[wave * 16 + mrow];
#pragma unroll
        for (int i = 0; i < 4; ++i) {
            const int r = r0 + quad * 4 + i;
            if (r < N)
                outF[(size_t)r * 64 + wave * 16 + mrow] = ah[i] + bh;
        }
    }
}

// ---------------------------------------------------------------------------
extern "C" void kernel_launch(void* const* d_in, const int* in_sizes, int n_in,
                              void* d_out, int out_size, void* d_ws, size_t ws_size,
                              hipStream_t stream)
{
    const float* x   = (const float*)d_in[0];
    const int* ei    = (const int*)d_in[1];
    const float* W1l = (const float*)d_in[2];
    const float* b1l = (const float*)d_in[3];
    const float* W1r = (const float*)d_in[4];
    const float* W2l = (const float*)d_in[5];
    const float* b2l = (const float*)d_in[6];
    const float* W2r = (const float*)d_in[7];
    const float* W3  = (const float*)d_in[8];
    const float* b3  = (const float*)d_in[9];
    float* out = (float*)d_out;

    const int N = in_sizes[0] / 128;   // 50000
    const int E = in_sizes[1] / 2;     // 640000
    const int* src = ei;
    const int* dst = ei + E;

    // workspace layout (all offsets 16B aligned):
    //   deg_i : n4*4 ints        partials: 64 ints
    //   rowptr: N+4 ints         cursor  : n4*4 ints
    //   csr   : E ints           xb/h1   : N*128 f16 each
    //   wb    : 5 f16 weight mats contiguous
    //   x8/h18: N*128 fp8 each (gather tables)
    const int n4 = (N + 3) / 4;
    int* deg_i    = (int*)d_ws;
    int* partials = deg_i + n4 * 4;
    int* rowptr   = partials + 64;
    int* cursor   = rowptr + N + 4;
    int* csr      = cursor + n4 * 4;
    unsigned short* xb   = (unsigned short*)(csr + E);
    unsigned short* h1   = xb + (size_t)N * 128;
    unsigned short* wb1l = h1 + (size_t)N * 128;
    unsigned short* wb1r = wb1l + 16384;
    unsigned short* wb2l = wb1r + 16384;
    unsigned short* wb2r = wb2l + 16384;
    unsigned short* wb3  = wb2r + 16384;
    unsigned char* x8    = (unsigned char*)(wb3 + 8192);
    unsigned char* h18   = x8 + (size_t)N * 128;

    const int lblk = (N + 15) / 16;             // fused layer: 1 tile/block
    const int eblk = (E + 255) / 256;
    const int NX4  = N * 32;                    // x in float4 units
    const int P    = (n4 + 255) / 256;          // scan blocks (<=64 for N<=65536)

    // ---- fused prologue: weight cvt + x cvt (f16+fp8) + deg zero ----
    {
        int total = WSEG + NX4 + n4;
        hipLaunchKernelGGL(prologue_kernel, dim3((total + 255) / 256), dim3(256), 0,
                           stream, W1l, W1r, W2l, W2r, W3, x, wb1l, xb, x8, deg_i,
                           NX4, n4);
    }

    // ---- CSR build (once; reused by both layers) ----
    hipLaunchKernelGGL(hist_kernel, dim3(eblk), dim3(256), 0, stream, dst, deg_i, E);
    hipLaunchKernelGGL(scan_partial_kernel, dim3(P), dim3(256), 0, stream,
                       deg_i, partials, N);
    hipLaunchKernelGGL(scan_apply_kernel, dim3(P), dim3(256), 0, stream,
                       deg_i, partials, rowptr, cursor, N, P);
    hipLaunchKernelGGL(fill_kernel, dim3(eblk), dim3(256), 0, stream,
                       src, dst, cursor, csr, E);

    // ---- fused layers (layer 2 carries the head) ----
    hipLaunchKernelGGL((sage_layer_kernel<true, false>), dim3(lblk), dim3(256), 0,
                       stream, xb, x8, rowptr, csr, wb1l, wb1r, b1l,
                       h1, h18, nullptr, nullptr, nullptr, N);
    hipLaunchKernelGGL((sage_layer_kernel<false, true>), dim3(lblk), dim3(256), 0,
                       stream, h1, h18, rowptr, csr, wb2l, wb2r, b2l,
                       nullptr, nullptr, wb3, b3, out, N);
}

// Round 13
// 258.508 us; speedup vs baseline: 1.0714x; 1.0173x over previous
//
#include <hip/hip_runtime.h>
#include <hip/hip_fp16.h>

// ---------------------------------------------------------------------------
// GNN_6305011991202: 2-layer GraphSAGE (mean aggr) + linear head. fp32 I/O.
//   h1 = relu(mean1 @ W1_l^T + b1_l + x  @ W1_r^T)
//   h2 = relu(mean2 @ W2_l^T + b2_l + h1 @ W2_r^T)
//   out = h2 @ W3^T + b3          (out: [50000, 64] fp32)
// R13: pair-interleaved gather chains. R12's 4-node batch was serialized by
// the register allocator (VGPR_Count=44 proved payloads never coexisted).
// Pairs need only +24 VGPRs: issue 8 idx loads, 8 feat loads, then consume
// A while B's loads fly -> pair cost ~ one latency chain instead of two.
// Keeps: fp8 gather table (128B rows), f16 GEMMs, head fused into layer 2.
// ---------------------------------------------------------------------------

typedef _Float16 f16x8 __attribute__((ext_vector_type(8)));
typedef float floatx4 __attribute__((ext_vector_type(4)));
typedef float floatx2 __attribute__((ext_vector_type(2)));

__device__ __forceinline__ unsigned short f2h(float f) {
    __half h = __float2half_rn(f);
    union { __half h; unsigned short s; } c; c.h = h; return c.s;
}
__device__ __forceinline__ __half2 u2h(unsigned u) {
    union { unsigned u; __half2 h; } c; c.u = u; return c.h;
}
__device__ __forceinline__ unsigned h2u(__half2 h) {
    union { __half2 h; unsigned u; } c; c.h = h; return c.u;
}
__device__ __forceinline__ __half2 shx(__half2 v, int m) {
    return u2h((unsigned)__shfl_xor((int)h2u(v), m, 64));
}
__device__ __forceinline__ ushort4 cvt4h(float4 v) {
    ushort4 o;
    o.x = f2h(v.x); o.y = f2h(v.y); o.z = f2h(v.z); o.w = f2h(v.w);
    return o;
}
__device__ __forceinline__ unsigned char f2fp8(float v) {
    return (unsigned char)(__builtin_amdgcn_cvt_pk_fp8_f32(v, v, 0, false) & 0xff);
}

// ---------------------------------------------------------------------------
// Fused prologue: convert 5 weight mats (f16, contiguous dst), x -> f16 AND
// fp8 tables, zero deg.
#define WSEG 18432
__global__ __launch_bounds__(256) void prologue_kernel(
    const float* __restrict__ W1l, const float* __restrict__ W1r,
    const float* __restrict__ W2l, const float* __restrict__ W2r,
    const float* __restrict__ W3,  const float* __restrict__ x,
    unsigned short* __restrict__ wb,   // 5 weight dsts contiguous
    unsigned short* __restrict__ xb,
    unsigned char* __restrict__ x8,
    int* __restrict__ deg, int NX4, int ND4)
{
    int i = blockIdx.x * 256 + threadIdx.x;
    if (i < WSEG) {
        const float* s; int l;
        if (i < 8192)       { if (i < 4096) { s = W1l; l = i; }
                              else          { s = W1r; l = i - 4096; } }
        else if (i < 16384) { if (i < 12288){ s = W2l; l = i - 8192; }
                              else          { s = W2r; l = i - 12288; } }
        else                { s = W3; l = i - 16384; }
        ((ushort4*)wb)[i] = cvt4h(((const float4*)s)[l]);
        return;
    }
    int j = i - WSEG;
    if (j < NX4) {
        float4 v = ((const float4*)x)[j];
        ((ushort4*)xb)[j] = cvt4h(v);
        unsigned u8 = __builtin_amdgcn_cvt_pk_fp8_f32(v.x, v.y, 0, false);
        u8 = __builtin_amdgcn_cvt_pk_fp8_f32(v.z, v.w, u8, true);
        ((unsigned*)x8)[j] = u8;
        return;
    }
    int k = j - NX4;
    if (k < ND4) ((int4*)deg)[k] = make_int4(0, 0, 0, 0);
}

// ---------------------------------------------------------------------------
// CSR build step 1: degree histogram over dst
__global__ __launch_bounds__(256) void hist_kernel(const int* __restrict__ dst,
                                                   int* __restrict__ deg, int E) {
    int e = blockIdx.x * 256 + threadIdx.x;
    if (e < E) atomicAdd(deg + dst[e], 1);
}

// CSR scan A: per-block sums (1024 elems/block)
__global__ __launch_bounds__(256) void scan_partial_kernel(
    const int* __restrict__ deg, int* __restrict__ partials, int N)
{
    __shared__ int ws[4];
    const int t = threadIdx.x, lane = t & 63, wave = t >> 6;
    const int i4 = blockIdx.x * 256 + t;
    const int n4 = (N + 3) / 4;
    int s = 0;
    if (i4 < n4) {
        int b = i4 * 4;
        if (b + 3 < N) {
            int4 v = ((const int4*)deg)[i4];
            s = v.x + v.y + v.z + v.w;
        } else {
            for (int q = 0; q < 4 && b + q < N; ++q) s += deg[b + q];
        }
    }
#pragma unroll
    for (int off = 32; off > 0; off >>= 1) s += __shfl_xor(s, off, 64);
    if (lane == 0) ws[wave] = s;
    __syncthreads();
    if (t == 0) partials[blockIdx.x] = ws[0] + ws[1] + ws[2] + ws[3];
}

// CSR scan B+C merged: each block redundantly reduces partials[< blockIdx]
// (P <= 64), re-scans its 1024 elems, writes rowptr & cursor.
__global__ __launch_bounds__(256) void scan_apply_kernel(
    const int* __restrict__ deg, const int* __restrict__ partials,
    int* __restrict__ rowptr, int* __restrict__ cursor, int N, int P)
{
    __shared__ int woff[4];
    __shared__ int s_base;
    const int t = threadIdx.x, lane = t & 63, wave = t >> 6;
    const int i4 = blockIdx.x * 256 + t;
    const int n4 = (N + 3) / 4;
    const int b = i4 * 4;

    if (wave == 0) {          // exclusive sum of block partials below us
        int v = (lane < P && lane < (int)blockIdx.x) ? partials[lane] : 0;
#pragma unroll
        for (int off = 32; off > 0; off >>= 1) v += __shfl_xor(v, off, 64);
        if (lane == 0) s_base = v;
    }

    int4 v = make_int4(0, 0, 0, 0);
    if (i4 < n4) {
        if (b + 3 < N) v = ((const int4*)deg)[i4];
        else {
            if (b + 0 < N) v.x = deg[b + 0];
            if (b + 1 < N) v.y = deg[b + 1];
            if (b + 2 < N) v.z = deg[b + 2];
        }
    }
    const int p1 = v.x, p2 = v.x + v.y, p3 = v.x + v.y + v.z;
    const int tsum = p3 + v.w;
    int incl = tsum;
#pragma unroll
    for (int off = 1; off < 64; off <<= 1) {
        int tt = __shfl_up(incl, off, 64);
        if (lane >= off) incl += tt;
    }
    const int texcl = incl - tsum;
    if (lane == 63) woff[wave] = incl;
    __syncthreads();
    int wo = 0;
#pragma unroll
    for (int w = 0; w < 4; ++w) if (w < wave) wo += woff[w];
    const int e = s_base + wo + texcl;
    if (blockIdx.x == 0 && t == 0) rowptr[0] = 0;
    if (b + 3 < N) {
        ((int4*)cursor)[i4] = make_int4(e, e + p1, e + p2, e + p3);
        rowptr[b + 1] = e + p1;
        rowptr[b + 2] = e + p2;
        rowptr[b + 3] = e + p3;
        rowptr[b + 4] = e + tsum;
    } else if (b < N) {
        if (b + 0 < N) { cursor[b + 0] = e;      rowptr[b + 1] = e + p1; }
        if (b + 1 < N) { cursor[b + 1] = e + p1; rowptr[b + 2] = e + p2; }
        if (b + 2 < N) { cursor[b + 2] = e + p2; rowptr[b + 3] = e + p3; }
    }
}

// CSR build: scatter src ids into neighbor lists
__global__ __launch_bounds__(256) void fill_kernel(const int* __restrict__ src,
                                                   const int* __restrict__ dst,
                                                   int* __restrict__ cursor,
                                                   int* __restrict__ csr, int E) {
    int e = blockIdx.x * 256 + threadIdx.x;
    if (e >= E) return;
    int pos = atomicAdd(cursor + dst[e], 1);
    csr[pos] = src[e];
}

// ---------------------------------------------------------------------------
// Fused SAGE layer (+optional head): 256 threads = 4 waves per 16-row tile.
// Phase 1 (wave w -> nodes r0+4w..+3), PAIR-interleaved chains:
//   nodes processed as 2 pairs; per pair: 8 csr-index loads (A,B), 8 feat
//   dwordx2 loads (A,B), consume A (B's loads still in flight), consume B.
//   Pair cost ~ one latency chain. lane = (slot grp = lane>>4, col = lane&15
//   covering 8 fp8 cols / 8B); OOB chunks zero-masked; tail (deg>16) keeps
//   the R10 chunk order -> per-node summation order unchanged.
//   Node end: pack f16, shfl_xor(16/32) cross-slot reduce, grp==0 -> LDS.
// Phase 2: wave w computes col-tiles {2w,2w+1} (dual Wl/Wr MFMA,
//   mfma_f32_16x16x32_f16), A from LDS, self f16 from global.
//   !HEAD: store f16 out (+fp8 copy if WFP8). HEAD: h2 tile -> LDS, barrier,
//   each wave does one 16-col head tile (A=sh2, B=W3) -> fp32 out.
template <bool WFP8, bool HEAD>
__global__ __launch_bounds__(256) void sage_layer_kernel(
    const unsigned short* __restrict__ feat,   // [N,128] f16 (self path)
    const unsigned char* __restrict__ feat8,   // [N,128] fp8 (gather path)
    const int* __restrict__ rowptr, const int* __restrict__ csr,
    const unsigned short* __restrict__ Wl,
    const unsigned short* __restrict__ Wr,
    const float* __restrict__ bias,
    unsigned short* __restrict__ out,          // [N,128] f16 (if !HEAD)
    unsigned char* __restrict__ out8,          // [N,128] fp8 (if WFP8)
    const unsigned short* __restrict__ W3,     // [64,128] f16 (if HEAD)
    const float* __restrict__ b3,              // [64] (if HEAD)
    float* __restrict__ outF,                  // [N,64] fp32 (if HEAD)
    int N)
{
    __shared__ unsigned short smean[16][136];
    __shared__ unsigned short sh2[HEAD ? 16 : 1][136];
    const int wave = threadIdx.x >> 6;
    const int lane = threadIdx.x & 63;
    const int r0 = blockIdx.x * 16;

    // ---- phase 1: this wave gathers 4 of the block's 16 nodes ----
    {
        const int grp = lane >> 4;          // neighbor slot 0..3
        const int col = lane & 15;          // 8-col group (8B of fp8)
        const unsigned char* fq = feat8 + col * 8;

        // rowptr window (wave-uniform -> scalar loads)
        int w[5];
#pragma unroll
        for (int q = 0; q < 5; ++q) {
            int n = r0 + wave * 4 + q;
            w[q] = rowptr[n < N ? n : N];   // rowptr has N+1 valid entries
        }

        // consume one node's first-16 payload + tail + reduce + LDS store
        auto consume = [&](int mi, int beg, int end, uint2 pay[4]) {
            const int deg = end - beg;
            floatx2 a0 = (floatx2)(0.f), a1 = (floatx2)(0.f);
            floatx2 a2 = (floatx2)(0.f), a3 = (floatx2)(0.f);
#pragma unroll
            for (int c = 0; c < 4; ++c) {
                const int j = beg + grp + c * 4;
                const unsigned m = (j < end) ? 0xffffffffu : 0u;
                uint2 p = pay[c];
                p.x &= m; p.y &= m;
                a0 += __builtin_amdgcn_cvt_pk_f32_fp8(p.x, false);
                a1 += __builtin_amdgcn_cvt_pk_f32_fp8(p.x, true);
                a2 += __builtin_amdgcn_cvt_pk_f32_fp8(p.y, false);
                a3 += __builtin_amdgcn_cvt_pk_f32_fp8(p.y, true);
            }
            for (int jA = beg + 16 + grp; jA < end; jA += 16) {
                const int jB = jA + 4, jC = jA + 8, jD = jA + 12;
                const unsigned mB = (jB < end) ? 0xffffffffu : 0u;
                const unsigned mC = (jC < end) ? 0xffffffffu : 0u;
                const unsigned mD = (jD < end) ? 0xffffffffu : 0u;
                const int iA = csr[jA];
                const int iB = csr[mB ? jB : beg];
                const int iC = csr[mC ? jC : beg];
                const int iD = csr[mD ? jD : beg];
                uint2 pA = *(const uint2*)(fq + (size_t)iA * 128);
                uint2 pB = *(const uint2*)(fq + (size_t)iB * 128);
                uint2 pC = *(const uint2*)(fq + (size_t)iC * 128);
                uint2 pD = *(const uint2*)(fq + (size_t)iD * 128);
                pB.x &= mB; pB.y &= mB;
                pC.x &= mC; pC.y &= mC;
                pD.x &= mD; pD.y &= mD;
                a0 += __builtin_amdgcn_cvt_pk_f32_fp8(pA.x, false);
                a1 += __builtin_amdgcn_cvt_pk_f32_fp8(pA.x, true);
                a2 += __builtin_amdgcn_cvt_pk_f32_fp8(pA.y, false);
                a3 += __builtin_amdgcn_cvt_pk_f32_fp8(pA.y, true);
                a0 += __builtin_amdgcn_cvt_pk_f32_fp8(pB.x, false);
                a1 += __builtin_amdgcn_cvt_pk_f32_fp8(pB.x, true);
                a2 += __builtin_amdgcn_cvt_pk_f32_fp8(pB.y, false);
                a3 += __builtin_amdgcn_cvt_pk_f32_fp8(pB.y, true);
                a0 += __builtin_amdgcn_cvt_pk_f32_fp8(pC.x, false);
                a1 += __builtin_amdgcn_cvt_pk_f32_fp8(pC.x, true);
                a2 += __builtin_amdgcn_cvt_pk_f32_fp8(pC.y, false);
                a3 += __builtin_amdgcn_cvt_pk_f32_fp8(pC.y, true);
                a0 += __builtin_amdgcn_cvt_pk_f32_fp8(pD.x, false);
                a1 += __builtin_amdgcn_cvt_pk_f32_fp8(pD.x, true);
                a2 += __builtin_amdgcn_cvt_pk_f32_fp8(pD.y, false);
                a3 += __builtin_amdgcn_cvt_pk_f32_fp8(pD.y, true);
            }
            __half2 c0 = __floats2half2_rn(a0.x, a0.y);
            __half2 c1 = __floats2half2_rn(a1.x, a1.y);
            __half2 c2 = __floats2half2_rn(a2.x, a2.y);
            __half2 c3 = __floats2half2_rn(a3.x, a3.y);
            c0 = __hadd2(c0, shx(c0, 16)); c0 = __hadd2(c0, shx(c0, 32));
            c1 = __hadd2(c1, shx(c1, 16)); c1 = __hadd2(c1, shx(c1, 32));
            c2 = __hadd2(c2, shx(c2, 16)); c2 = __hadd2(c2, shx(c2, 32));
            c3 = __hadd2(c3, shx(c3, 16)); c3 = __hadd2(c3, shx(c3, 32));
            if (grp == 0) {
                const float inv = (deg > 0) ? 1.0f / (float)deg : 0.0f;
                uint4 o;
                o.x = h2u(__floats2half2_rn(__low2float(c0) * inv,
                                            __high2float(c0) * inv));
                o.y = h2u(__floats2half2_rn(__low2float(c1) * inv,
                                            __high2float(c1) * inv));
                o.z = h2u(__floats2half2_rn(__low2float(c2) * inv,
                                            __high2float(c2) * inv));
                o.w = h2u(__floats2half2_rn(__low2float(c3) * inv,
                                            __high2float(c3) * inv));
                *(uint4*)&smean[mi][col * 8] = o;
            }
        };

        // two pairs; within a pair both nodes' loads are issued before
        // either is consumed -> pair cost ~ one latency chain
#pragma unroll
        for (int p = 0; p < 2; ++p) {
            const int qa = 2 * p, qb = 2 * p + 1;
            const int begA = w[qa], endA = w[qa + 1];
            const int begB = w[qb], endB = w[qb + 1];
            int idxA[4], idxB[4];
#pragma unroll
            for (int c = 0; c < 4; ++c) {
                const int j = begA + grp + c * 4;
                idxA[c] = csr[j < endA ? j : 0];
            }
#pragma unroll
            for (int c = 0; c < 4; ++c) {
                const int j = begB + grp + c * 4;
                idxB[c] = csr[j < endB ? j : 0];
            }
            uint2 payA[4], payB[4];
#pragma unroll
            for (int c = 0; c < 4; ++c)
                payA[c] = *(const uint2*)(fq + (size_t)idxA[c] * 128);
#pragma unroll
            for (int c = 0; c < 4; ++c)
                payB[c] = *(const uint2*)(fq + (size_t)idxB[c] * 128);
            consume(wave * 4 + qa, begA, endA, payA);
            consume(wave * 4 + qb, begB, endB, payB);
        }
    }
    __syncthreads();

    // ---- phase 2: this wave computes col-tiles 2*wave, 2*wave+1 ----
    const int mrow = lane & 15;
    const int quad = lane >> 4;
    int selfRow = r0 + mrow;
    if (selfRow >= N) selfRow = N - 1;      // partial-tile clamp (loads only)
    const size_t rowS = (size_t)selfRow * 128;

    floatx4 acc0 = (floatx4)(0.0f), acc1 = (floatx4)(0.0f);
    const int t0 = wave * 2, t1 = wave * 2 + 1;

#pragma unroll
    for (int kk = 0; kk < 4; ++kk) {
        const int k = kk * 32 + quad * 8;
        f16x8 aA = *(const f16x8*)&smean[mrow][k];
        f16x8 aS = *(const f16x8*)(feat + rowS + k);
        f16x8 bl0 = *(const f16x8*)(Wl + (size_t)(t0 * 16 + mrow) * 128 + k);
        acc0 = __builtin_amdgcn_mfma_f32_16x16x32_f16(aA, bl0, acc0, 0, 0, 0);
        f16x8 br0 = *(const f16x8*)(Wr + (size_t)(t0 * 16 + mrow) * 128 + k);
        acc0 = __builtin_amdgcn_mfma_f32_16x16x32_f16(aS, br0, acc0, 0, 0, 0);
        f16x8 bl1 = *(const f16x8*)(Wl + (size_t)(t1 * 16 + mrow) * 128 + k);
        acc1 = __builtin_amdgcn_mfma_f32_16x16x32_f16(aA, bl1, acc1, 0, 0, 0);
        f16x8 br1 = *(const f16x8*)(Wr + (size_t)(t1 * 16 + mrow) * 128 + k);
        acc1 = __builtin_amdgcn_mfma_f32_16x16x32_f16(aS, br1, acc1, 0, 0, 0);
    }

    const float b0 = bias[t0 * 16 + mrow];
    const float b1 = bias[t1 * 16 + mrow];
#pragma unroll
    for (int i = 0; i < 4; ++i) {
        const int r = r0 + quad * 4 + i;
        const float v0 = fmaxf(acc0[i] + b0, 0.0f);
        const float v1 = fmaxf(acc1[i] + b1, 0.0f);
        if (HEAD) {
            sh2[quad * 4 + i][t0 * 16 + mrow] = f2h(v0);
            sh2[quad * 4 + i][t1 * 16 + mrow] = f2h(v1);
        } else if (r < N) {
            out[(size_t)r * 128 + t0 * 16 + mrow] = f2h(v0);
            out[(size_t)r * 128 + t1 * 16 + mrow] = f2h(v1);
            if (WFP8) {
                out8[(size_t)r * 128 + t0 * 16 + mrow] = f2fp8(v0);
                out8[(size_t)r * 128 + t1 * 16 + mrow] = f2fp8(v1);
            }
        }
    }

    // ---- optional fused head: out = h2 @ W3^T + b3 (fp32, 64 cols) ----
    if (HEAD) {
        __syncthreads();
        floatx4 ah = (floatx4)(0.0f);
#pragma unroll
        for (int kk = 0; kk < 4; ++kk) {
            const int k = kk * 32 + quad * 8;
            f16x8 aA = *(const f16x8*)&sh2[mrow][k];
            f16x8 b = *(const f16x8*)(W3 + (size_t)(wave * 16 + mrow) * 128 + k);
            ah = __builtin_amdgcn_mfma_f32_16x16x32_f16(aA, b, ah, 0, 0, 0);
        }
        const float bh = b3[wave * 16 + mrow];
#pragma unroll
        for (int i = 0; i < 4; ++i) {
            const int r = r0 + quad * 4 + i;
            if (r < N)
                outF[(size_t)r * 64 + wave * 16 + mrow] = ah[i] + bh;
        }
    }
}

// ---------------------------------------------------------------------------
extern "C" void kernel_launch(void* const* d_in, const int* in_sizes, int n_in,
                              void* d_out, int out_size, void* d_ws, size_t ws_size,
                              hipStream_t stream)
{
    const float* x   = (const float*)d_in[0];
    const int* ei    = (const int*)d_in[1];
    const float* W1l = (const float*)d_in[2];
    const float* b1l = (const float*)d_in[3];
    const float* W1r = (const float*)d_in[4];
    const float* W2l = (const float*)d_in[5];
    const float* b2l = (const float*)d_in[6];
    const float* W2r = (const float*)d_in[7];
    const float* W3  = (const float*)d_in[8];
    const float* b3  = (const float*)d_in[9];
    float* out = (float*)d_out;

    const int N = in_sizes[0] / 128;   // 50000
    const int E = in_sizes[1] / 2;     // 640000
    const int* src = ei;
    const int* dst = ei + E;

    // workspace layout (all offsets 16B aligned):
    //   deg_i : n4*4 ints        partials: 64 ints
    //   rowptr: N+4 ints         cursor  : n4*4 ints
    //   csr   : E ints           xb/h1   : N*128 f16 each
    //   wb    : 5 f16 weight mats contiguous
    //   x8/h18: N*128 fp8 each (gather tables)
    const int n4 = (N + 3) / 4;
    int* deg_i    = (int*)d_ws;
    int* partials = deg_i + n4 * 4;
    int* rowptr   = partials + 64;
    int* cursor   = rowptr + N + 4;
    int* csr      = cursor + n4 * 4;
    unsigned short* xb   = (unsigned short*)(csr + E);
    unsigned short* h1   = xb + (size_t)N * 128;
    unsigned short* wb1l = h1 + (size_t)N * 128;
    unsigned short* wb1r = wb1l + 16384;
    unsigned short* wb2l = wb1r + 16384;
    unsigned short* wb2r = wb2l + 16384;
    unsigned short* wb3  = wb2r + 16384;
    unsigned char* x8    = (unsigned char*)(wb3 + 8192);
    unsigned char* h18   = x8 + (size_t)N * 128;

    const int lblk = (N + 15) / 16;             // fused layer: 1 tile/block
    const int eblk = (E + 255) / 256;
    const int NX4  = N * 32;                    // x in float4 units
    const int P    = (n4 + 255) / 256;          // scan blocks (<=64 for N<=65536)

    // ---- fused prologue: weight cvt + x cvt (f16+fp8) + deg zero ----
    {
        int total = WSEG + NX4 + n4;
        hipLaunchKernelGGL(prologue_kernel, dim3((total + 255) / 256), dim3(256), 0,
                           stream, W1l, W1r, W2l, W2r, W3, x, wb1l, xb, x8, deg_i,
                           NX4, n4);
    }

    // ---- CSR build (once; reused by both layers) ----
    hipLaunchKernelGGL(hist_kernel, dim3(eblk), dim3(256), 0, stream, dst, deg_i, E);
    hipLaunchKernelGGL(scan_partial_kernel, dim3(P), dim3(256), 0, stream,
                       deg_i, partials, N);
    hipLaunchKernelGGL(scan_apply_kernel, dim3(P), dim3(256), 0, stream,
                       deg_i, partials, rowptr, cursor, N, P);
    hipLaunchKernelGGL(fill_kernel, dim3(eblk), dim3(256), 0, stream,
                       src, dst, cursor, csr, E);

    // ---- fused layers (layer 2 carries the head) ----
    hipLaunchKernelGGL((sage_layer_kernel<true, false>), dim3(lblk), dim3(256), 0,
                       stream, xb, x8, rowptr, csr, wb1l, wb1r, b1l,
                       h1, h18, nullptr, nullptr, nullptr, N);
    hipLaunchKernelGGL((sage_layer_kernel<false, true>), dim3(lblk), dim3(256), 0,
                       stream, h1, h18, rowptr, csr, wb2l, wb2r, b2l,
                       nullptr, nullptr, wb3, b3, out, N);
}